// Round 15
// baseline (182.019 us; speedup 1.0000x reference)
//
#include <hip/hip_runtime.h>
#include <hip/hip_bf16.h>

#define B_ROWS 131072
#define H 128
#define SLAB 32
#define NSLAB 8                  // 256 rows per block strip
#define NBLK 512

typedef __bf16 bf16x8 __attribute__((ext_vector_type(8)));
typedef float f32x4 __attribute__((ext_vector_type(4)));

#define LOG2E 1.4426950408889634f

__device__ __forceinline__ float fast_sigmoid(float v) {
    return __builtin_amdgcn_rcpf(1.0f + __builtin_amdgcn_exp2f(-LOG2E * v));
}
__device__ __forceinline__ float fast_tanh(float v) {
    return 1.0f - 2.0f * __builtin_amdgcn_rcpf(1.0f + __builtin_amdgcn_exp2f(2.0f * LOG2E * v));
}

struct WPtrs {
    const float* wx[4];
    const float* wh[4];
    const float* bx[4];
    const float* bh[4];
};

// Wcat[n][k]: n = gate*128 + unit, k in [0,256) = [X-k | h-k]. bsum[n] = bx+bh.
__global__ __launch_bounds__(256) void prep_weights(WPtrs p, __bf16* __restrict__ wcat,
                                                    float* __restrict__ bsum) {
    int n = blockIdx.x;
    int k = threadIdx.x;
    int g = n >> 7, r = n & 127;
    float v = (k < H) ? p.wx[g][r * H + k] : p.wh[g][r * H + (k - H)];
    wcat[n * 256 + k] = (__bf16)v;
    if (k == 0) bsum[n] = p.bx[g][r] + p.bh[g][r];
}

// R15 = R12 skeleton with SLAB 16->32. Rationale (R12 vs R13): at SLAB=16 the
// per-slab weight L2 re-stream (1.9us) and HBM stage (1.6us) ADD up to the
// measured 2.77us cadence. At SLAB=32 weights amortize 2x -> L2 (1.9us/32rows)
// < HBM (3.3us/32rows): the stream hides. Barrier lockstep cost per row halves.
// Weight loads deliberately LEFT to the compiler to sink into the K-loop
// (pinning them was neutral-to-worse: R13).
__global__ __launch_bounds__(512, 1) void lstm_fused(
    const float* __restrict__ X, const float* __restrict__ Hp, const float* __restrict__ Cp,
    const __bf16* __restrict__ Wcat, const float* __restrict__ Bsum,
    float* __restrict__ out)
{
    __shared__ char abuf[2][SLAB * 512];    // 2 x 16 KB bf16 [X|h] slab, XOR-swizzled

    const int t = threadIdx.x;
    const int lane = t & 63;
    const int wv = t >> 6;                  // 0..7: unit group
    const int l16 = lane & 15;
    const int kg = lane >> 4;               // 0..3
    const long base = (long)blockIdx.x * (SLAB * NSLAB);
    const long c_off = (long)B_ROWS * H;
    const int j = wv * 16 + l16;            // this lane's unit (all 4 gates)
    const __bf16* wbase = Wcat + (long)j * 256 + kg * 8;

    float bias[4];
#pragma unroll
    for (int g = 0; g < 4; ++g) bias[g] = Bsum[g * H + j];

    // staging map: thread t -> rows {t>>5, 16+(t>>5)}, 16B-slot t&31 (0..15 X, 16..31 h)
    const int s_r = t >> 5;
    const int s_g8 = t & 31;

    auto stage_load = [&](float4* L, long srow) {
#pragma unroll
        for (int q = 0; q < 2; ++q) {
            int row = q * 16 + s_r;
            const float* sp = (s_g8 < 16) ? (X + (srow + row) * H + s_g8 * 8)
                                          : (Hp + (srow + row) * H + (s_g8 - 16) * 8);
            L[q * 2]     = *(const float4*)sp;
            L[q * 2 + 1] = *(const float4*)(sp + 4);
        }
    };
    auto write_slab = [&](char* buf, const float4* W) {
#pragma unroll
        for (int q = 0; q < 2; ++q) {
            int row = q * 16 + s_r;
            union { __bf16 e[8]; bf16x8 v; } u;
            float4 lo = W[q * 2], hi = W[q * 2 + 1];
            u.e[0] = (__bf16)lo.x; u.e[1] = (__bf16)lo.y;
            u.e[2] = (__bf16)lo.z; u.e[3] = (__bf16)lo.w;
            u.e[4] = (__bf16)hi.x; u.e[5] = (__bf16)hi.y;
            u.e[6] = (__bf16)hi.z; u.e[7] = (__bf16)hi.w;
            *(bf16x8*)(buf + row * 512 + ((s_g8 ^ (row & 7)) << 4)) = u.v;
        }
    };
    auto load_cp = [&](float* c, long srow) {
#pragma unroll
        for (int q = 0; q < 2; ++q)
#pragma unroll
            for (int r = 0; r < 4; ++r)
                c[q * 4 + r] = Cp[(srow + q * 16 + kg * 4 + r) * H + j];
    };

    float4 R[4];
    float cpv[8], cpn[8];

    // prologue
    stage_load(R, base);                    // slab 0
    load_cp(cpv, base);
    write_slab(abuf[0], R);                 // auto vmcnt wait on R only
    stage_load(R, base + SLAB);             // slab 1 in flight

    for (int s = 0; s < NSLAB; ++s) {
        const long srow = base + (long)s * SLAB;
        const int cur = s & 1;

        // barrier: prior-body ds_reads done (lgkm), all waves synced; vmcnt untouched
        asm volatile("s_waitcnt lgkmcnt(0)\n\ts_barrier" ::: "memory");

        if (s + 1 < NSLAB) {
            write_slab(abuf[cur ^ 1], R);           // waits vmcnt for R (1 cadence old)
            load_cp(cpn, srow + SLAB);
            if (s + 2 < NSLAB) stage_load(R, srow + 2 * SLAB);
        }

        const char* ac = abuf[cur];
        f32x4 acc[4][2] = {};
#pragma unroll
        for (int kc = 0; kc < 8; ++kc) {
            bf16x8 av[2];
#pragma unroll
            for (int rt = 0; rt < 2; ++rt) {
                int row = rt * 16 + l16;
                av[rt] = *(const bf16x8*)(ac + row * 512 + (((kc * 4 + kg) ^ (row & 7)) << 4));
            }
#pragma unroll
            for (int g = 0; g < 4; ++g) {
                bf16x8 bv = *(const bf16x8*)(wbase + g * (128 * 256) + kc * 32);
                acc[g][0] = __builtin_amdgcn_mfma_f32_16x16x32_bf16(av[0], bv, acc[g][0], 0, 0, 0);
                acc[g][1] = __builtin_amdgcn_mfma_f32_16x16x32_bf16(av[1], bv, acc[g][1], 0, 0, 0);
            }
        }

        // epilogue: gates lane-local (C/D row=(lane>>4)*4+reg, col=lane&15)
#pragma unroll
        for (int rt = 0; rt < 2; ++rt) {
#pragma unroll
            for (int r = 0; r < 4; ++r) {
                long row = srow + rt * 16 + kg * 4 + r;
                float fg = acc[0][rt][r] + bias[0];
                float ig = acc[1][rt][r] + bias[1];
                float cg = acc[2][rt][r] + bias[2];
                float og = acc[3][rt][r] + bias[3];
                float ft = fast_sigmoid(fg);
                float it = fast_sigmoid(ig);
                float cc = fast_tanh(cg);
                float ot = fast_sigmoid(og);
                float ct = ft * cpv[rt * 4 + r] + it * cc;
                float ht = ot * fast_tanh(ct);
                out[row * H + j] = ht;
                out[c_off + row * H + j] = ct;
            }
        }
#pragma unroll
        for (int r = 0; r < 8; ++r) cpv[r] = cpn[r];
    }
}

extern "C" void kernel_launch(void* const* d_in, const int* in_sizes, int n_in,
                              void* d_out, int out_size, void* d_ws, size_t ws_size,
                              hipStream_t stream) {
    const float* X  = (const float*)d_in[0];
    const float* Hp = (const float*)d_in[1];
    const float* Cp = (const float*)d_in[2];
    WPtrs p;
    p.wx[0] = (const float*)d_in[3];  p.bx[0] = (const float*)d_in[4];
    p.wh[0] = (const float*)d_in[5];  p.bh[0] = (const float*)d_in[6];
    p.wx[1] = (const float*)d_in[7];  p.bx[1] = (const float*)d_in[8];
    p.wh[1] = (const float*)d_in[9];  p.bh[1] = (const float*)d_in[10];
    p.wx[2] = (const float*)d_in[11]; p.bx[2] = (const float*)d_in[12];
    p.wh[2] = (const float*)d_in[13]; p.bh[2] = (const float*)d_in[14];
    p.wx[3] = (const float*)d_in[15]; p.bx[3] = (const float*)d_in[16];
    p.wh[3] = (const float*)d_in[17]; p.bh[3] = (const float*)d_in[18];

    __bf16* wcat = (__bf16*)d_ws;
    float*  bsum = (float*)((char*)d_ws + 512 * 256 * 2);

    prep_weights<<<512, 256, 0, stream>>>(p, wcat, bsum);
    lstm_fused<<<NBLK, 512, 0, stream>>>(X, Hp, Cp, wcat, bsum, (float*)d_out);
}